// Round 4
// baseline (13608.902 us; speedup 1.0000x reference)
//
#include <hip/hip_runtime.h>
#include <cstddef>
#include <cstdint>

namespace {

constexpr int Hd = 512;   // hidden
constexpr int Bd = 256;   // batch
constexpr int Td = 512;   // seq len
constexpr int Vd = 2048;  // 4*H gate rows
constexpr int NRG = 32;   // row-groups (producers per bg-group)

typedef _Float16 f16x8 __attribute__((ext_vector_type(8)));
typedef float f32x4 __attribute__((ext_vector_type(4)));

__device__ __forceinline__ float sigm(float z) { return 1.0f / (1.0f + __expf(-z)); }
__device__ __forceinline__ float tanh_fast(float z) {
    return 1.0f - 2.0f / (1.0f + __expf(2.0f * z));
}

__device__ __forceinline__ void gl2lds16(const _Float16* g, _Float16* l) {
    __builtin_amdgcn_global_load_lds(
        (const __attribute__((address_space(1))) uint32_t*)(const void*)g,
        (__attribute__((address_space(3))) uint32_t*)(void*)l,
        16, 0, 0);
}

// Split W[4H,H] (torch row s = q*H + j) into fp16 hi/lo with row permutation
// v = 4*j + q; fold biases bb[v] = bih+bhh, wx[v] = Wih.
__global__ __launch_bounds__(256) void prep_weights(
    const float* __restrict__ Wsrc, const float* __restrict__ bih,
    const float* __restrict__ bhh, const float* __restrict__ wih,
    _Float16* __restrict__ W1, _Float16* __restrict__ W2,
    float* __restrict__ bb, float* __restrict__ wx)
{
    const int idx = blockIdx.x * 256 + threadIdx.x;  // over Vd*Hd
    const int v = idx >> 9;
    const int k = idx & 511;
    const int j = v >> 2, q = v & 3;
    const int s = q * Hd + j;
    const float w = Wsrc[(size_t)s * Hd + k];
    const _Float16 w1 = (_Float16)w;
    W1[idx] = w1;
    W2[idx] = (_Float16)(w - (float)w1);
    if (k == 0) {
        bb[v] = bih[s] + bhh[s];
        wx[v] = wih[s];
    }
}

// Persistent sequence kernel: runs all Td steps of one LSTM (enc or dec).
// Grid 256 = 8 bg (batch-groups of 32, bg = bid&7 for XCD affinity) x
// 32 rg (row-groups of 64 v-rows = 16 hidden units). 256 threads = 4 waves.
// k-split: wave wv owns k-slice [wv*128, wv*128+128); its W fragments (hi+lo)
// are register-resident for the whole kernel (32 KB/wave = 128 VGPRs).
// Per step: inter-block sync (per-bg monotonic counter, acq/rel device
// atomics) -> stage h slice to LDS (swizzled via pre-swizzled global src) ->
// MFMA partials -> cross-wave k-reduce via LDS overlay -> epilogue (c in
// registers, h split+stored, decoder projection via shfl+atomics).
__global__ __launch_bounds__(256, 1) void lstm_seq(
    const _Float16* __restrict__ W1, const _Float16* __restrict__ W2, // [2048][512]
    const float* __restrict__ bb, const float* __restrict__ wx,       // [2048]
    const float* __restrict__ x,                                      // [B][T]
    _Float16* __restrict__ h1b0, _Float16* __restrict__ h1b1,         // [B][H]
    _Float16* __restrict__ h2b0, _Float16* __restrict__ h2b1,
    const float* __restrict__ linW, const float* __restrict__ linb,
    float* __restrict__ out, int* __restrict__ cntArr, int is_dec)
{
    __shared__ alignas(16) char smem[65536];
    _Float16* h1t = (_Float16*)smem;             // [32 rows][512 k] swizzled
    _Float16* h2t = (_Float16*)(smem + 32768);
    f32x4* red    = (f32x4*)smem;                // overlay: [4 wv][8 tile][64 l]
    float* outp   = (float*)(smem + 32768);      // overlay: [4 wv][16]

    const int tid = threadIdx.x;
    const int l   = tid & 63;
    const int wv  = tid >> 6;
    const int r16 = l & 15;
    const int g2  = l >> 4;
    const int key = r16 & 7;
    const int bg  = blockIdx.x & 7;
    const int rg  = blockIdx.x >> 3;
    const int v0  = rg * 64;
    const int b0  = bg * 32;
    int* myCnt = cntArr + bg * 32;   // padded to 128B stride

    // ---- persistent W fragments: [half][rt][sub], rt=row-tile, sub=k-subtile
    f16x8 WA[2][4][4];
#pragma unroll
    for (int rt = 0; rt < 4; ++rt)
#pragma unroll
        for (int sub = 0; sub < 4; ++sub) {
            const size_t off =
                (size_t)(v0 + rt * 16 + r16) * Hd + wv * 128 + sub * 32 + g2 * 8;
            WA[0][rt][sub] = *(const f16x8*)(W1 + off);
            WA[1][rt][sub] = *(const f16x8*)(W2 + off);
        }

    // ---- persistent epilogue constants; wave owns row-tiles {rt0,rt1}, col ct
    const int ct  = wv >> 1;
    const int rt0 = 2 * (wv & 1);
    const int rt1 = rt0 + 1;
    const int j0  = rg * 16 + rt0 * 4 + g2;
    const int j1  = rg * 16 + rt1 * 4 + g2;
    const int bme = b0 + ct * 16 + r16;          // this lane's batch
    const float4 bias0 = *(const float4*)(bb + 4 * j0);
    const float4 bias1 = *(const float4*)(bb + 4 * j1);
    const float4 wxv0  = *(const float4*)(wx + 4 * j0);
    const float4 wxv1  = *(const float4*)(wx + 4 * j1);
    const float lw0 = linW[j0], lw1 = linW[j1];
    const float lb = linb[0];
    float c0 = 0.0f, c1 = 0.0f;                  // cell state: registers only

    for (int t = 0; t < Td; ++t) {
        const _Float16* h1i = (t & 1) ? h1b1 : h1b0;
        const _Float16* h2i = (t & 1) ? h2b1 : h2b0;
        _Float16* h1o = (t & 1) ? h1b0 : h1b1;
        _Float16* h2o = (t & 1) ? h2b0 : h2b1;

        // ---- wait for all 32 producers of this bg-group to publish h_t
        if (t > 0) {
            if (tid == 0) {
                int spins = 0;
                while (__hip_atomic_load(myCnt, __ATOMIC_ACQUIRE,
                                         __HIP_MEMORY_SCOPE_AGENT) < NRG * t) {
                    __builtin_amdgcn_s_sleep(1);
                    if (++spins > (1 << 24)) break;   // failsafe: fail visibly, not hang
                }
            }
            __syncthreads();
        }

        // ---- stage h slice (32 batches x 512 k, both halves) into LDS.
        // Pre-swizzled global source, linear LDS dest (chunk' = chunk ^ (row&7)).
#pragma unroll
        for (int i = 0; i < 8; ++i) {
            const int r = wv * 8 + i;
            const int src = (b0 + r) * Hd + ((l ^ (r & 7)) * 8);
            gl2lds16(h1i + src, h1t + r * Hd);
            gl2lds16(h2i + src, h2t + r * Hd);
        }
        __syncthreads();

        // ---- MFMA partials over this wave's k-slice
        f32x4 acc[4][2];
#pragma unroll
        for (int rt = 0; rt < 4; ++rt) {
            acc[rt][0] = (f32x4){0.f, 0.f, 0.f, 0.f};
            acc[rt][1] = (f32x4){0.f, 0.f, 0.f, 0.f};
        }
#pragma unroll
        for (int sub = 0; sub < 4; ++sub) {
            const int chunk = wv * 16 + sub * 4 + g2;
            f16x8 P[2], Q[2];
#pragma unroll
            for (int cc = 0; cc < 2; ++cc) {
                const int bl = cc * 16 + r16;
                const int slot = chunk ^ key;     // bl&7 == r16&7 == key
                P[cc] = *(const f16x8*)(h1t + bl * Hd + slot * 8);
                Q[cc] = *(const f16x8*)(h2t + bl * Hd + slot * 8);
            }
#pragma unroll
            for (int rt = 0; rt < 4; ++rt)
#pragma unroll
                for (int cc = 0; cc < 2; ++cc) {
                    acc[rt][cc] = __builtin_amdgcn_mfma_f32_16x16x32_f16(
                        WA[0][rt][sub], P[cc], acc[rt][cc], 0, 0, 0);
                    acc[rt][cc] = __builtin_amdgcn_mfma_f32_16x16x32_f16(
                        WA[0][rt][sub], Q[cc], acc[rt][cc], 0, 0, 0);
                    acc[rt][cc] = __builtin_amdgcn_mfma_f32_16x16x32_f16(
                        WA[1][rt][sub], P[cc], acc[rt][cc], 0, 0, 0);
                }
        }
        __syncthreads();   // all ds_reads of h done; LDS reusable

        // ---- cross-wave k-reduction via LDS overlay
#pragma unroll
        for (int rt = 0; rt < 4; ++rt)
#pragma unroll
            for (int cc = 0; cc < 2; ++cc)
                red[(wv * 8 + rt * 2 + cc) * 64 + l] = acc[rt][cc];
        __syncthreads();

        f32x4 s0 = (f32x4){0.f, 0.f, 0.f, 0.f};
        f32x4 s1 = (f32x4){0.f, 0.f, 0.f, 0.f};
#pragma unroll
        for (int wvp = 0; wvp < 4; ++wvp) {
            s0 += red[(wvp * 8 + rt0 * 2 + ct) * 64 + l];
            s1 += red[(wvp * 8 + rt1 * 2 + ct) * 64 + l];
        }

        // ---- epilogue: gates -> c (regs) -> h -> split fp16 hi/lo -> store
        const float xb = x[(size_t)bme * Td + t];
        float hn0, hn1;
        {
            const float gi = s0[0] + bias0.x + xb * wxv0.x;
            const float gf = s0[1] + bias0.y + xb * wxv0.y;
            const float gg = s0[2] + bias0.z + xb * wxv0.z;
            const float go = s0[3] + bias0.w + xb * wxv0.w;
            c0 = sigm(gf) * c0 + sigm(gi) * tanh_fast(gg);
            hn0 = sigm(go) * tanh_fast(c0);
        }
        {
            const float gi = s1[0] + bias1.x + xb * wxv1.x;
            const float gf = s1[1] + bias1.y + xb * wxv1.y;
            const float gg = s1[2] + bias1.z + xb * wxv1.z;
            const float go = s1[3] + bias1.w + xb * wxv1.w;
            c1 = sigm(gf) * c1 + sigm(gi) * tanh_fast(gg);
            hn1 = sigm(go) * tanh_fast(c1);
        }
        const _Float16 a0 = (_Float16)hn0;
        const _Float16 a1 = (_Float16)hn1;
        h1o[(size_t)bme * Hd + j0] = a0;
        h1o[(size_t)bme * Hd + j1] = a1;
        h2o[(size_t)bme * Hd + j0] = (_Float16)(hn0 - (float)a0);
        h2o[(size_t)bme * Hd + j1] = (_Float16)(hn1 - (float)a1);

        if (is_dec) {
            float p = hn0 * lw0 + hn1 * lw1;
            p += __shfl_xor(p, 16);
            p += __shfl_xor(p, 32);
            if (g2 == 0) outp[wv * 16 + r16] = p;
            __syncthreads();
            if (tid < 32) {
                const int cc = tid >> 4, bl = tid & 15;
                float s = outp[(cc * 2) * 16 + bl] + outp[(cc * 2 + 1) * 16 + bl];
                if (rg == 0) s += lb;
                atomicAdd(out + (size_t)(b0 + tid) * Td + t, s);
            }
        }

        // ---- publish h_{t+1}: drain stores (syncthreads), then release-add
        __syncthreads();
        if (tid == 0)
            __hip_atomic_fetch_add(myCnt, 1, __ATOMIC_RELEASE,
                                   __HIP_MEMORY_SCOPE_AGENT);
    }
}

} // namespace

extern "C" void kernel_launch(void* const* d_in, const int* in_sizes, int n_in,
                              void* d_out, int out_size, void* d_ws, size_t ws_size,
                              hipStream_t stream) {
    (void)in_sizes; (void)n_in; (void)ws_size;
    const float* x    = (const float*)d_in[0];
    const float* eWih = (const float*)d_in[1];
    const float* eWhh = (const float*)d_in[2];
    const float* ebih = (const float*)d_in[3];
    const float* ebhh = (const float*)d_in[4];
    const float* dWih = (const float*)d_in[5];
    const float* dWhh = (const float*)d_in[6];
    const float* dbih = (const float*)d_in[7];
    const float* dbhh = (const float*)d_in[8];
    const float* linW = (const float*)d_in[9];
    const float* linb = (const float*)d_in[10];
    float* out = (float*)d_out;

    // ---- workspace layout (~9.1 MB)
    char* p = (char*)d_ws;
    int* cntE = (int*)p;                         p += 2048;   // 8 bg x 128B
    int* cntD = (int*)p;                         p += 2048;
    _Float16* h1b0 = (_Float16*)p;               p += (size_t)Bd * Hd * 2;
    _Float16* h2b0 = (_Float16*)p;               p += (size_t)Bd * Hd * 2;
    _Float16* h1b1 = (_Float16*)p;               p += (size_t)Bd * Hd * 2;
    _Float16* h2b1 = (_Float16*)p;               p += (size_t)Bd * Hd * 2;
    _Float16* eW1 = (_Float16*)p;                p += (size_t)Vd * Hd * 2;
    _Float16* eW2 = (_Float16*)p;                p += (size_t)Vd * Hd * 2;
    _Float16* dW1 = (_Float16*)p;                p += (size_t)Vd * Hd * 2;
    _Float16* dW2 = (_Float16*)p;                p += (size_t)Vd * Hd * 2;
    float* ebb = (float*)p;                      p += Vd * 4;
    float* ewx = (float*)p;                      p += Vd * 4;
    float* dbb = (float*)p;                      p += Vd * 4;
    float* dwx = (float*)p;                      p += Vd * 4;

    // zero: counters + initial h (buf0). buf1 is written before read.
    hipMemsetAsync(d_ws, 0, 4096 + 2 * (size_t)Bd * Hd * 2, stream);
    hipMemsetAsync(d_out, 0, (size_t)out_size * sizeof(float), stream);

    prep_weights<<<dim3(Vd * Hd / 256), dim3(256), 0, stream>>>(
        eWhh, ebih, ebhh, eWih, eW1, eW2, ebb, ewx);
    prep_weights<<<dim3(Vd * Hd / 256), dim3(256), 0, stream>>>(
        dWhh, dbih, dbhh, dWih, dW1, dW2, dbb, dwx);

    // encoder: h starts zero (buf0), c starts zero (registers)
    lstm_seq<<<dim3(256), dim3(256), 0, stream>>>(
        eW1, eW2, ebb, ewx, x, h1b0, h1b1, h2b0, h2b1,
        linW, linb, out, cntE, 0);

    // decoder: h carries over (enc step 511 wrote buf0), c resets (registers)
    lstm_seq<<<dim3(256), dim3(256), 0, stream>>>(
        dW1, dW2, dbb, dwx, x, h1b0, h1b1, h2b0, h2b1,
        linW, linb, out, cntD, 1);
}

// Round 5
// 13157.892 us; speedup vs baseline: 1.0343x; 1.0343x over previous
//
#include <hip/hip_runtime.h>
#include <cstddef>
#include <cstdint>

namespace {

constexpr int Hd = 512;   // hidden
constexpr int Bd = 256;   // batch
constexpr int Td = 512;   // seq len
constexpr int Vd = 2048;  // 4*H gate rows
constexpr int NRG = 32;   // row-groups (producers per bg-group)

typedef _Float16 f16x8 __attribute__((ext_vector_type(8)));
typedef float f32x4 __attribute__((ext_vector_type(4)));

__device__ __forceinline__ float sigm(float z) { return 1.0f / (1.0f + __expf(-z)); }
__device__ __forceinline__ float tanh_fast(float z) {
    return 1.0f - 2.0f / (1.0f + __expf(2.0f * z));
}

__device__ __forceinline__ void gl2lds16(const _Float16* g, _Float16* l) {
    __builtin_amdgcn_global_load_lds(
        (const __attribute__((address_space(1))) uint32_t*)(const void*)g,
        (__attribute__((address_space(3))) uint32_t*)(void*)l,
        16, 0, 0);
}

__device__ __forceinline__ void nt_store_h(_Float16 v, _Float16* p) {
    union { _Float16 f; short s; } u; u.f = v;
    __builtin_nontemporal_store(u.s, (short*)p);
}

// Split W[4H,H] (torch row s = q*H + j) into fp16 hi/lo with row permutation
// v = 4*j + q; fold biases bb[v] = bih+bhh, wx[v] = Wih.
__global__ __launch_bounds__(256) void prep_weights(
    const float* __restrict__ Wsrc, const float* __restrict__ bih,
    const float* __restrict__ bhh, const float* __restrict__ wih,
    _Float16* __restrict__ W1, _Float16* __restrict__ W2,
    float* __restrict__ bb, float* __restrict__ wx)
{
    const int idx = blockIdx.x * 256 + threadIdx.x;  // over Vd*Hd
    const int v = idx >> 9;
    const int k = idx & 511;
    const int j = v >> 2, q = v & 3;
    const int s = q * Hd + j;
    const float w = Wsrc[(size_t)s * Hd + k];
    const _Float16 w1 = (_Float16)w;
    W1[idx] = w1;
    W2[idx] = (_Float16)(w - (float)w1);
    if (k == 0) {
        bb[v] = bih[s] + bhh[s];
        wx[v] = wih[s];
    }
}

// Persistent sequence kernel: all Td steps of one LSTM (enc or dec).
// Grid 256 = 8 bg x 32 rg. 256 threads = 4 waves; wave wv owns k-slice
// [wv*128, +128), W fragments register-resident for the whole kernel.
// Sync per step: producers nt-store h, release-add a per-bg counter;
// consumers poll with RELAXED agent loads (no per-poll cache inv), then
// issue ONE acquire fence before staging h.
__global__ __launch_bounds__(256, 1) void lstm_seq(
    const _Float16* __restrict__ W1, const _Float16* __restrict__ W2, // [2048][512]
    const float* __restrict__ bb, const float* __restrict__ wx,       // [2048]
    const float* __restrict__ x,                                      // [B][T]
    _Float16* __restrict__ h1b0, _Float16* __restrict__ h1b1,         // [B][H]
    _Float16* __restrict__ h2b0, _Float16* __restrict__ h2b1,
    const float* __restrict__ linW, const float* __restrict__ linb,
    float* __restrict__ out, int* __restrict__ cntArr, int is_dec)
{
    __shared__ alignas(16) char smem[65536];
    _Float16* h1t = (_Float16*)smem;             // [32 rows][512 k] swizzled
    _Float16* h2t = (_Float16*)(smem + 32768);
    f32x4* red    = (f32x4*)smem;                // overlay: [4 wv][8 tile][64 l]
    float* outp   = (float*)(smem + 32768);      // overlay: [4 wv][16]

    const int tid = threadIdx.x;
    const int l   = tid & 63;
    const int wv  = tid >> 6;
    const int r16 = l & 15;
    const int g2  = l >> 4;
    const int key = r16 & 7;
    const int bg  = blockIdx.x & 7;
    const int rg  = blockIdx.x >> 3;
    const int v0  = rg * 64;
    const int b0  = bg * 32;
    int* myCnt = cntArr + bg * 32;   // padded to 128B stride

    // ---- persistent W fragments: [half][rt][sub]
    f16x8 WA[2][4][4];
#pragma unroll
    for (int rt = 0; rt < 4; ++rt)
#pragma unroll
        for (int sub = 0; sub < 4; ++sub) {
            const size_t off =
                (size_t)(v0 + rt * 16 + r16) * Hd + wv * 128 + sub * 32 + g2 * 8;
            WA[0][rt][sub] = *(const f16x8*)(W1 + off);
            WA[1][rt][sub] = *(const f16x8*)(W2 + off);
        }

    // ---- persistent epilogue constants; wave owns row-tiles {rt0,rt1}, col ct
    const int ct  = wv >> 1;
    const int rt0 = 2 * (wv & 1);
    const int rt1 = rt0 + 1;
    const int j0  = rg * 16 + rt0 * 4 + g2;
    const int j1  = rg * 16 + rt1 * 4 + g2;
    const int bme = b0 + ct * 16 + r16;          // this lane's batch
    const float4 bias0 = *(const float4*)(bb + 4 * j0);
    const float4 bias1 = *(const float4*)(bb + 4 * j1);
    const float4 wxv0  = *(const float4*)(wx + 4 * j0);
    const float4 wxv1  = *(const float4*)(wx + 4 * j1);
    const float lw0 = linW[j0], lw1 = linW[j1];
    const float lb = linb[0];
    float c0 = 0.0f, c1 = 0.0f;                  // cell state: registers only
    int lastSeen = 0;                            // tid0 only: cached counter

    for (int t = 0; t < Td; ++t) {
        const _Float16* h1i = (t & 1) ? h1b1 : h1b0;
        const _Float16* h2i = (t & 1) ? h2b1 : h2b0;
        _Float16* h1o = (t & 1) ? h1b0 : h1b1;
        _Float16* h2o = (t & 1) ? h2b0 : h2b1;

        // x for this step: issue before the poll; completes during spin
        const float xb = x[(size_t)bme * Td + t];

        // ---- wait for all 32 producers of this bg-group to publish h_t.
        // RELAXED polls (agent-scope load bypasses stale caches, but no
        // invalidate per poll) + ONE acquire fence once satisfied.
        if (t > 0) {
            if (tid == 0) {
                const int target = NRG * t;
                if (lastSeen < target) {
                    int spins = 0;
                    int v;
                    do {
                        v = __hip_atomic_load(myCnt, __ATOMIC_RELAXED,
                                              __HIP_MEMORY_SCOPE_AGENT);
                        if (v >= target) break;
                        __builtin_amdgcn_s_sleep(1);
                    } while (++spins < (1 << 20));   // failsafe: fail visibly
                    lastSeen = v;
                }
                __builtin_amdgcn_fence(__ATOMIC_ACQUIRE, "agent");
            }
            __syncthreads();
        }

        // ---- stage h slice (32 batches x 512 k, both halves) into LDS.
        // Pre-swizzled global source, linear LDS dest (chunk' = chunk ^ (row&7)).
#pragma unroll
        for (int i = 0; i < 8; ++i) {
            const int r = wv * 8 + i;
            const int src = (b0 + r) * Hd + ((l ^ (r & 7)) * 8);
            gl2lds16(h1i + src, h1t + r * Hd);
            gl2lds16(h2i + src, h2t + r * Hd);
        }
        __syncthreads();

        // ---- MFMA partials over this wave's k-slice
        f32x4 acc[4][2];
#pragma unroll
        for (int rt = 0; rt < 4; ++rt) {
            acc[rt][0] = (f32x4){0.f, 0.f, 0.f, 0.f};
            acc[rt][1] = (f32x4){0.f, 0.f, 0.f, 0.f};
        }
#pragma unroll
        for (int sub = 0; sub < 4; ++sub) {
            const int chunk = wv * 16 + sub * 4 + g2;
            f16x8 P[2], Q[2];
#pragma unroll
            for (int cc = 0; cc < 2; ++cc) {
                const int bl = cc * 16 + r16;
                const int slot = chunk ^ key;     // bl&7 == r16&7 == key
                P[cc] = *(const f16x8*)(h1t + bl * Hd + slot * 8);
                Q[cc] = *(const f16x8*)(h2t + bl * Hd + slot * 8);
            }
#pragma unroll
            for (int rt = 0; rt < 4; ++rt)
#pragma unroll
                for (int cc = 0; cc < 2; ++cc) {
                    acc[rt][cc] = __builtin_amdgcn_mfma_f32_16x16x32_f16(
                        WA[0][rt][sub], P[cc], acc[rt][cc], 0, 0, 0);
                    acc[rt][cc] = __builtin_amdgcn_mfma_f32_16x16x32_f16(
                        WA[0][rt][sub], Q[cc], acc[rt][cc], 0, 0, 0);
                    acc[rt][cc] = __builtin_amdgcn_mfma_f32_16x16x32_f16(
                        WA[1][rt][sub], P[cc], acc[rt][cc], 0, 0, 0);
                }
        }
        __syncthreads();   // all ds_reads of h done; LDS reusable

        // ---- cross-wave k-reduction via LDS overlay
#pragma unroll
        for (int rt = 0; rt < 4; ++rt)
#pragma unroll
            for (int cc = 0; cc < 2; ++cc)
                red[(wv * 8 + rt * 2 + cc) * 64 + l] = acc[rt][cc];
        __syncthreads();

        f32x4 s0 = (f32x4){0.f, 0.f, 0.f, 0.f};
        f32x4 s1 = (f32x4){0.f, 0.f, 0.f, 0.f};
#pragma unroll
        for (int wvp = 0; wvp < 4; ++wvp) {
            s0 += red[(wvp * 8 + rt0 * 2 + ct) * 64 + l];
            s1 += red[(wvp * 8 + rt1 * 2 + ct) * 64 + l];
        }

        // ---- epilogue: gates -> c (regs) -> h -> split fp16 hi/lo
        float hn0, hn1;
        {
            const float gi = s0[0] + bias0.x + xb * wxv0.x;
            const float gf = s0[1] + bias0.y + xb * wxv0.y;
            const float gg = s0[2] + bias0.z + xb * wxv0.z;
            const float go = s0[3] + bias0.w + xb * wxv0.w;
            c0 = sigm(gf) * c0 + sigm(gi) * tanh_fast(gg);
            hn0 = sigm(go) * tanh_fast(c0);
        }
        {
            const float gi = s1[0] + bias1.x + xb * wxv1.x;
            const float gf = s1[1] + bias1.y + xb * wxv1.y;
            const float gg = s1[2] + bias1.z + xb * wxv1.z;
            const float go = s1[3] + bias1.w + xb * wxv1.w;
            c1 = sigm(gf) * c1 + sigm(gi) * tanh_fast(gg);
            hn1 = sigm(go) * tanh_fast(c1);
        }
        const _Float16 a0 = (_Float16)hn0;
        const _Float16 a1 = (_Float16)hn1;
        nt_store_h(a0, h1o + (size_t)bme * Hd + j0);
        nt_store_h(a1, h1o + (size_t)bme * Hd + j1);
        nt_store_h((_Float16)(hn0 - (float)a0), h2o + (size_t)bme * Hd + j0);
        nt_store_h((_Float16)(hn1 - (float)a1), h2o + (size_t)bme * Hd + j1);

        // ---- publish h_{t+1} ASAP: barrier drains all waves' stores
        // (compiler emits vmcnt(0) before s_barrier), then release-add.
        __syncthreads();
        if (tid == 0)
            __hip_atomic_fetch_add(myCnt, 1, __ATOMIC_RELEASE,
                                   __HIP_MEMORY_SCOPE_AGENT);

        // ---- decoder projection: off the inter-block critical path
        if (is_dec) {
            float p = hn0 * lw0 + hn1 * lw1;
            p += __shfl_xor(p, 16);
            p += __shfl_xor(p, 32);
            if (g2 == 0) outp[wv * 16 + r16] = p;
            __syncthreads();
            if (tid < 32) {
                const int cc = tid >> 4, bl = tid & 15;
                float s = outp[(cc * 2) * 16 + bl] + outp[(cc * 2 + 1) * 16 + bl];
                if (rg == 0) s += lb;
                atomicAdd(out + (size_t)(b0 + tid) * Td + t, s);
            }
            __syncthreads();   // protect outp overlay before next-step staging
        }
    }
}

} // namespace

extern "C" void kernel_launch(void* const* d_in, const int* in_sizes, int n_in,
                              void* d_out, int out_size, void* d_ws, size_t ws_size,
                              hipStream_t stream) {
    (void)in_sizes; (void)n_in; (void)ws_size;
    const float* x    = (const float*)d_in[0];
    const float* eWih = (const float*)d_in[1];
    const float* eWhh = (const float*)d_in[2];
    const float* ebih = (const float*)d_in[3];
    const float* ebhh = (const float*)d_in[4];
    const float* dWih = (const float*)d_in[5];
    const float* dWhh = (const float*)d_in[6];
    const float* dbih = (const float*)d_in[7];
    const float* dbhh = (const float*)d_in[8];
    const float* linW = (const float*)d_in[9];
    const float* linb = (const float*)d_in[10];
    float* out = (float*)d_out;

    // ---- workspace layout (~9.1 MB)
    char* p = (char*)d_ws;
    int* cntE = (int*)p;                         p += 2048;   // 8 bg x 128B
    int* cntD = (int*)p;                         p += 2048;
    _Float16* h1b0 = (_Float16*)p;               p += (size_t)Bd * Hd * 2;
    _Float16* h2b0 = (_Float16*)p;               p += (size_t)Bd * Hd * 2;
    _Float16* h1b1 = (_Float16*)p;               p += (size_t)Bd * Hd * 2;
    _Float16* h2b1 = (_Float16*)p;               p += (size_t)Bd * Hd * 2;
    _Float16* eW1 = (_Float16*)p;                p += (size_t)Vd * Hd * 2;
    _Float16* eW2 = (_Float16*)p;                p += (size_t)Vd * Hd * 2;
    _Float16* dW1 = (_Float16*)p;                p += (size_t)Vd * Hd * 2;
    _Float16* dW2 = (_Float16*)p;                p += (size_t)Vd * Hd * 2;
    float* ebb = (float*)p;                      p += Vd * 4;
    float* ewx = (float*)p;                      p += Vd * 4;
    float* dbb = (float*)p;                      p += Vd * 4;
    float* dwx = (float*)p;                      p += Vd * 4;

    // zero: counters + initial h (buf0). buf1 is written before read.
    hipMemsetAsync(d_ws, 0, 4096 + 2 * (size_t)Bd * Hd * 2, stream);
    hipMemsetAsync(d_out, 0, (size_t)out_size * sizeof(float), stream);

    prep_weights<<<dim3(Vd * Hd / 256), dim3(256), 0, stream>>>(
        eWhh, ebih, ebhh, eWih, eW1, eW2, ebb, ewx);
    prep_weights<<<dim3(Vd * Hd / 256), dim3(256), 0, stream>>>(
        dWhh, dbih, dbhh, dWih, dW1, dW2, dbb, dwx);

    // encoder: h starts zero (buf0), c starts zero (registers)
    lstm_seq<<<dim3(256), dim3(256), 0, stream>>>(
        eW1, eW2, ebb, ewx, x, h1b0, h1b1, h2b0, h2b1,
        linW, linb, out, cntE, 0);

    // decoder: h carries over (enc step 511 wrote buf0), c resets (registers)
    lstm_seq<<<dim3(256), dim3(256), 0, stream>>>(
        dW1, dW2, dbb, dwx, x, h1b0, h1b1, h2b0, h2b1,
        linW, linb, out, cntD, 1);
}

// Round 6
// 5040.613 us; speedup vs baseline: 2.6999x; 2.6104x over previous
//
#include <hip/hip_runtime.h>
#include <cstddef>
#include <cstdint>

namespace {

constexpr int Hd = 512;   // hidden
constexpr int Bd = 256;   // batch
constexpr int Td = 512;   // seq len
constexpr int Vd = 2048;  // 4*H gate rows

typedef _Float16 f16x8 __attribute__((ext_vector_type(8)));
typedef float f32x4 __attribute__((ext_vector_type(4)));
typedef uint32_t u32x4 __attribute__((ext_vector_type(4)));

__device__ __forceinline__ float sigm(float z) { return 1.0f / (1.0f + __expf(-z)); }
__device__ __forceinline__ float tanh_fast(float z) {
    return 1.0f - 2.0f / (1.0f + __expf(2.0f * z));
}

// ---- cross-XCD coherent accesses (write-through / cache-bypassing).
// sc0 sc1 = coherent at device scope on gfx950; avoids buffer_wbl2/inv.
__device__ __forceinline__ u32x4 ld_coh_x4(const uint32_t* p) {
    u32x4 r;
    asm volatile("global_load_dwordx4 %0, %1, off sc0 sc1"
                 : "=v"(r) : "v"(p) : "memory");
    return r;
}
__device__ __forceinline__ uint32_t ld_coh(const uint32_t* p) {
    uint32_t r;
    asm volatile("global_load_dword %0, %1, off sc0 sc1\n\ts_waitcnt vmcnt(0)"
                 : "=v"(r) : "v"(p) : "memory");
    return r;
}
__device__ __forceinline__ void st_coh(uint32_t* p, uint32_t v) {
    asm volatile("global_store_dword %0, %1, off sc0 sc1"
                 :: "v"(p), "v"(v) : "memory");
}

// Split W[4H,H] (torch row s = q*H + j) into fp16 hi/lo with row permutation
// v = 4*j + q; fold biases bb[v] = bih+bhh, wx[v] = Wih.
__global__ __launch_bounds__(256) void prep_weights(
    const float* __restrict__ Wsrc, const float* __restrict__ bih,
    const float* __restrict__ bhh, const float* __restrict__ wih,
    _Float16* __restrict__ W1, _Float16* __restrict__ W2,
    float* __restrict__ bb, float* __restrict__ wx)
{
    const int idx = blockIdx.x * 256 + threadIdx.x;  // over Vd*Hd
    const int v = idx >> 9;
    const int k = idx & 511;
    const int j = v >> 2, q = v & 3;
    const int s = q * Hd + j;
    const float w = Wsrc[(size_t)s * Hd + k];
    const _Float16 w1 = (_Float16)w;
    W1[idx] = w1;
    W2[idx] = (_Float16)(w - (float)w1);
    if (k == 0) {
        bb[v] = bih[s] + bhh[s];
        wx[v] = wih[s];
    }
}

// Persistent sequence kernel: all Td steps of one LSTM (enc or dec).
// Grid 256 = 8 bg x 32 rg; 4 waves; wave wv owns k-slice [wv*128,+128),
// W fragments register-resident. h exchanged as packed (hi16,lo16) u32,
// write-through sc0sc1 stores / cache-bypassing sc0sc1 loads; per-producer
// flag words (no RMW, no fences, no L2 writeback/invalidate anywhere).
__global__ __launch_bounds__(256, 1) void lstm_seq(
    const _Float16* __restrict__ W1, const _Float16* __restrict__ W2, // [2048][512]
    const float* __restrict__ bb, const float* __restrict__ wx,       // [2048]
    const float* __restrict__ x,                                      // [B][T]
    uint32_t* __restrict__ hP0, uint32_t* __restrict__ hP1,           // [B][H] packed
    const float* __restrict__ linW, const float* __restrict__ linb,
    float* __restrict__ out, uint32_t* __restrict__ flagArr, int is_dec)
{
    __shared__ alignas(16) char smem[65536];
    _Float16* h1t = (_Float16*)smem;             // [32 rows][512 k] swizzled
    _Float16* h2t = (_Float16*)(smem + 32768);
    f32x4* red    = (f32x4*)smem;                // overlay: [4 wv][8 tile][64 l]
    float* outp   = (float*)(smem + 32768);      // overlay: [4 wv][16]
    __shared__ float xs[32][516];                // x slice, padded rows

    const int tid = threadIdx.x;
    const int l   = tid & 63;
    const int wv  = tid >> 6;
    const int r16 = l & 15;
    const int g2  = l >> 4;
    const int key = r16 & 7;
    const int bg  = blockIdx.x & 7;
    const int rg  = blockIdx.x >> 3;
    const int v0  = rg * 64;
    const int b0  = bg * 32;
    uint32_t* flags = flagArr + bg * 32 * 32;    // 32 flags x 128B stride
    uint32_t* myFlag = flags + rg * 32;

    // ---- persistent W fragments: [half][rt][sub]
    f16x8 WA[2][4][4];
#pragma unroll
    for (int rt = 0; rt < 4; ++rt)
#pragma unroll
        for (int sub = 0; sub < 4; ++sub) {
            const size_t off =
                (size_t)(v0 + rt * 16 + r16) * Hd + wv * 128 + sub * 32 + g2 * 8;
            WA[0][rt][sub] = *(const f16x8*)(W1 + off);
            WA[1][rt][sub] = *(const f16x8*)(W2 + off);
        }

    // ---- preload this block's x slice into LDS (once)
    const int sRow = tid >> 3;       // 0..31
    const int c8   = tid & 7;        // 0..7
#pragma unroll
    for (int i = 0; i < 16; ++i) {
        const int c4 = i * 8 + c8;   // float4 index 0..127
        *(float4*)&xs[sRow][c4 * 4] =
            *(const float4*)(x + (size_t)(b0 + sRow) * Td + c4 * 4);
    }

    // ---- persistent epilogue constants; wave owns row-tiles {rt0,rt1}, col ct
    const int ct  = wv >> 1;
    const int rt0 = 2 * (wv & 1);
    const int rt1 = rt0 + 1;
    const int j0  = rg * 16 + rt0 * 4 + g2;
    const int j1  = rg * 16 + rt1 * 4 + g2;
    const int bml = ct * 16 + r16;               // local batch index
    const float4 bias0 = *(const float4*)(bb + 4 * j0);
    const float4 bias1 = *(const float4*)(bb + 4 * j1);
    const float4 wxv0  = *(const float4*)(wx + 4 * j0);
    const float4 wxv1  = *(const float4*)(wx + 4 * j1);
    const float lw0 = linW[j0], lw1 = linW[j1];
    const float lb = linb[0];
    float c0 = 0.0f, c1 = 0.0f;                  // cell state: registers only

    for (int t = 0; t < Td; ++t) {
        const uint32_t* hPi = (t & 1) ? hP1 : hP0;
        uint32_t* hPo = (t & 1) ? hP0 : hP1;

        // ---- wait for all 32 producers of this bg-group (parallel lane poll,
        // coherent loads, no fences). Producer k's flag >= t means h_t ready.
        if (t > 0) {
            if (wv == 0) {
                const uint32_t* fp = flags + (l & 31) * 32;
                int spins = 0;
                while ((int)ld_coh(fp) < t) {
                    __builtin_amdgcn_s_sleep(2);
                    if (++spins > (1 << 20)) break;   // fail visibly, not hang
                }
            }
            __syncthreads();
        }

        // ---- stage h slice: coherent loads -> split pairs -> swizzled LDS
        {
            const uint32_t* srcRow = hPi + (size_t)(b0 + sRow) * Hd;
            u32x4 q[16];
#pragma unroll
            for (int i = 0; i < 8; ++i) {
                const int c = i * 8 + c8;            // 16B chunk index 0..63
                q[2 * i]     = ld_coh_x4(srcRow + c * 8);
                q[2 * i + 1] = ld_coh_x4(srcRow + c * 8 + 4);
            }
            asm volatile("s_waitcnt vmcnt(0)" ::: "memory");
            __builtin_amdgcn_sched_barrier(0);
            const int rkey = sRow & 7;
            _Float16* d1row = h1t + sRow * Hd;
            _Float16* d2row = h2t + sRow * Hd;
#pragma unroll
            for (int i = 0; i < 8; ++i) {
                const int c = i * 8 + c8;
                const int slot = c ^ rkey;
                const u32x4 A = q[2 * i], B = q[2 * i + 1];
                u32x4 lo, hi;
                lo[0] = (A[0] & 0xffffu) | (A[1] << 16);
                lo[1] = (A[2] & 0xffffu) | (A[3] << 16);
                lo[2] = (B[0] & 0xffffu) | (B[1] << 16);
                lo[3] = (B[2] & 0xffffu) | (B[3] << 16);
                hi[0] = (A[0] >> 16) | (A[1] & 0xffff0000u);
                hi[1] = (A[2] >> 16) | (A[3] & 0xffff0000u);
                hi[2] = (B[0] >> 16) | (B[1] & 0xffff0000u);
                hi[3] = (B[2] >> 16) | (B[3] & 0xffff0000u);
                *(u32x4*)(d1row + slot * 8) = lo;
                *(u32x4*)(d2row + slot * 8) = hi;
            }
        }
        __syncthreads();

        // ---- MFMA partials over this wave's k-slice (hi*hi + hi*lo + lo*hi)
        f32x4 acc[4][2];
#pragma unroll
        for (int rt = 0; rt < 4; ++rt) {
            acc[rt][0] = (f32x4){0.f, 0.f, 0.f, 0.f};
            acc[rt][1] = (f32x4){0.f, 0.f, 0.f, 0.f};
        }
#pragma unroll
        for (int sub = 0; sub < 4; ++sub) {
            const int chunk = wv * 16 + sub * 4 + g2;
            f16x8 P[2], Q[2];
#pragma unroll
            for (int cc = 0; cc < 2; ++cc) {
                const int bl = cc * 16 + r16;
                const int slot = chunk ^ key;     // bl&7 == r16&7 == key
                P[cc] = *(const f16x8*)(h1t + bl * Hd + slot * 8);
                Q[cc] = *(const f16x8*)(h2t + bl * Hd + slot * 8);
            }
#pragma unroll
            for (int rt = 0; rt < 4; ++rt)
#pragma unroll
                for (int cc = 0; cc < 2; ++cc) {
                    acc[rt][cc] = __builtin_amdgcn_mfma_f32_16x16x32_f16(
                        WA[0][rt][sub], P[cc], acc[rt][cc], 0, 0, 0);
                    acc[rt][cc] = __builtin_amdgcn_mfma_f32_16x16x32_f16(
                        WA[0][rt][sub], Q[cc], acc[rt][cc], 0, 0, 0);
                    acc[rt][cc] = __builtin_amdgcn_mfma_f32_16x16x32_f16(
                        WA[1][rt][sub], P[cc], acc[rt][cc], 0, 0, 0);
                }
        }
        __syncthreads();   // all ds_reads of h done; LDS reusable

        // ---- cross-wave k-reduction via LDS overlay
#pragma unroll
        for (int rt = 0; rt < 4; ++rt)
#pragma unroll
            for (int cc = 0; cc < 2; ++cc)
                red[(wv * 8 + rt * 2 + cc) * 64 + l] = acc[rt][cc];
        __syncthreads();

        f32x4 s0 = (f32x4){0.f, 0.f, 0.f, 0.f};
        f32x4 s1 = (f32x4){0.f, 0.f, 0.f, 0.f};
#pragma unroll
        for (int wvp = 0; wvp < 4; ++wvp) {
            s0 += red[(wvp * 8 + rt0 * 2 + ct) * 64 + l];
            s1 += red[(wvp * 8 + rt1 * 2 + ct) * 64 + l];
        }

        // ---- epilogue: gates -> c (regs) -> h -> packed coherent store
        const float xb = xs[bml][t];
        float hn0, hn1;
        {
            const float gi = s0[0] + bias0.x + xb * wxv0.x;
            const float gf = s0[1] + bias0.y + xb * wxv0.y;
            const float gg = s0[2] + bias0.z + xb * wxv0.z;
            const float go = s0[3] + bias0.w + xb * wxv0.w;
            c0 = sigm(gf) * c0 + sigm(gi) * tanh_fast(gg);
            hn0 = sigm(go) * tanh_fast(c0);
        }
        {
            const float gi = s1[0] + bias1.x + xb * wxv1.x;
            const float gf = s1[1] + bias1.y + xb * wxv1.y;
            const float gg = s1[2] + bias1.z + xb * wxv1.z;
            const float go = s1[3] + bias1.w + xb * wxv1.w;
            c1 = sigm(gf) * c1 + sigm(gi) * tanh_fast(gg);
            hn1 = sigm(go) * tanh_fast(c1);
        }
        union { _Float16 h[2]; uint32_t u; } pk;
        pk.h[0] = (_Float16)hn0;
        pk.h[1] = (_Float16)(hn0 - (float)pk.h[0]);
        st_coh(hPo + (size_t)(b0 + bml) * Hd + j0, pk.u);
        pk.h[0] = (_Float16)hn1;
        pk.h[1] = (_Float16)(hn1 - (float)pk.h[1 - 1]);  // recompute below safely
        // (rewrite cleanly to avoid aliasing confusion)
        {
            union { _Float16 h[2]; uint32_t u; } pk1;
            pk1.h[0] = (_Float16)hn1;
            pk1.h[1] = (_Float16)(hn1 - (float)pk1.h[0]);
            st_coh(hPo + (size_t)(b0 + bml) * Hd + j1, pk1.u);
        }

        // drain our asm stores (compiler doesn't track them), then publish
        asm volatile("s_waitcnt vmcnt(0)" ::: "memory");
        __syncthreads();
        if (tid == 0) st_coh(myFlag, (uint32_t)(t + 1));

        // ---- decoder projection: off the inter-block critical path
        if (is_dec) {
            float p = hn0 * lw0 + hn1 * lw1;
            p += __shfl_xor(p, 16);
            p += __shfl_xor(p, 32);
            if (g2 == 0) outp[wv * 16 + r16] = p;
            __syncthreads();
            if (tid < 32) {
                const int cc = tid >> 4, bl = tid & 15;
                float s = outp[(cc * 2) * 16 + bl] + outp[(cc * 2 + 1) * 16 + bl];
                if (rg == 0) s += lb;
                atomicAdd(out + (size_t)(b0 + tid) * Td + t, s);
            }
            __syncthreads();   // protect outp overlay before next-step staging
        }
    }
}

} // namespace

extern "C" void kernel_launch(void* const* d_in, const int* in_sizes, int n_in,
                              void* d_out, int out_size, void* d_ws, size_t ws_size,
                              hipStream_t stream) {
    (void)in_sizes; (void)n_in; (void)ws_size;
    const float* x    = (const float*)d_in[0];
    const float* eWih = (const float*)d_in[1];
    const float* eWhh = (const float*)d_in[2];
    const float* ebih = (const float*)d_in[3];
    const float* ebhh = (const float*)d_in[4];
    const float* dWih = (const float*)d_in[5];
    const float* dWhh = (const float*)d_in[6];
    const float* dbih = (const float*)d_in[7];
    const float* dbhh = (const float*)d_in[8];
    const float* linW = (const float*)d_in[9];
    const float* linb = (const float*)d_in[10];
    float* out = (float*)d_out;

    // ---- workspace layout (~9.2 MB); flags+hP0 first so one memset covers
    char* p = (char*)d_ws;
    uint32_t* cntE = (uint32_t*)p;               p += 8 * 32 * 128;  // 32KB
    uint32_t* cntD = (uint32_t*)p;               p += 8 * 32 * 128;  // 32KB
    uint32_t* hP0 = (uint32_t*)p;                p += (size_t)Bd * Hd * 4;
    uint32_t* hP1 = (uint32_t*)p;                p += (size_t)Bd * Hd * 4;
    _Float16* eW1 = (_Float16*)p;                p += (size_t)Vd * Hd * 2;
    _Float16* eW2 = (_Float16*)p;                p += (size_t)Vd * Hd * 2;
    _Float16* dW1 = (_Float16*)p;                p += (size_t)Vd * Hd * 2;
    _Float16* dW2 = (_Float16*)p;                p += (size_t)Vd * Hd * 2;
    float* ebb = (float*)p;                      p += Vd * 4;
    float* ewx = (float*)p;                      p += Vd * 4;
    float* dbb = (float*)p;                      p += Vd * 4;
    float* dwx = (float*)p;                      p += Vd * 4;

    // zero: flags (both phases) + initial h (hP0). hP1 written before read.
    hipMemsetAsync(d_ws, 0, 2 * 8 * 32 * 128 + (size_t)Bd * Hd * 4, stream);
    hipMemsetAsync(d_out, 0, (size_t)out_size * sizeof(float), stream);

    prep_weights<<<dim3(Vd * Hd / 256), dim3(256), 0, stream>>>(
        eWhh, ebih, ebhh, eWih, eW1, eW2, ebb, ewx);
    prep_weights<<<dim3(Vd * Hd / 256), dim3(256), 0, stream>>>(
        dWhh, dbih, dbhh, dWih, dW1, dW2, dbb, dwx);

    // encoder: h starts zero (hP0), c zero (registers)
    lstm_seq<<<dim3(256), dim3(256), 0, stream>>>(
        eW1, eW2, ebb, ewx, x, hP0, hP1, linW, linb, out, cntE, 0);

    // decoder: h carries over (enc step 511 wrote hP0), c resets (registers)
    lstm_seq<<<dim3(256), dim3(256), 0, stream>>>(
        dW1, dW2, dbb, dwx, x, hP0, hP1, linW, linb, out, cntD, 1);
}